// Round 5
// baseline (461.968 us; speedup 1.0000x reference)
//
#include <hip/hip_runtime.h>

// Problem constants
constexpr int QN  = 10001;   // questions (Q+1)
constexpr int BB  = 512;     // batch
constexpr int TT  = 200;     // seq len
constexpr int QPB = 16;      // questions per block in k_perq

__device__ __forceinline__ float sigm(float x) { return 1.f / (1.f + __expf(-x)); }
__device__ __forceinline__ float tanh_fast(float x) { return 1.f - 2.f / (1.f + __expf(2.f * x)); }

// ---------------------------------------------------------------------------
// Kernel 1: tiny precomputed tables (unchanged).
// ---------------------------------------------------------------------------
__global__ void k_tables(const float* __restrict__ E_c, const float* __restrict__ E_it,
                         const float* __restrict__ E_ut, const float* __restrict__ E_nh,
                         const float* __restrict__ W_fuse, const float* __restrict__ b_fuse,
                         const float* __restrict__ W_ih, const float* __restrict__ b_ih,
                         float* __restrict__ T_c, float* __restrict__ T_it,
                         float* __restrict__ T_ut, float* __restrict__ T_nh, float* __restrict__ T_na,
                         float* __restrict__ bias0, float* __restrict__ Vcorr)
{
    int blk = blockIdx.x, j = threadIdx.x; // 192 threads
    __shared__ float s_e[64];
    __shared__ float s_t[64];

    if (blk < 201) {
        if (j < 64) s_e[j] = E_c[blk * 64 + j];
        __syncthreads();
        float a = 0.f;
        #pragma unroll
        for (int k = 0; k < 64; k++) a += W_ih[j * 320 + 64 + k] * s_e[k];
        T_c[blk * 192 + j] = a;
    } else if (blk < 302) {
        int r = blk - 201;
        if (j < 64) s_e[j] = E_it[r * 64 + j];
        __syncthreads();
        float a = 0.f;
        #pragma unroll
        for (int k = 0; k < 64; k++) a += W_ih[j * 320 + 192 + k] * s_e[k];
        T_it[r * 192 + j] = a;
    } else if (blk < 605) {
        int which = (blk - 302) / 101;
        int r     = (blk - 302) % 101;
        const float* E = (which == 0) ? E_ut : E_nh;
        int fofs = which * 64;
        if (j < 64) s_e[j] = E[r * 64 + j];
        __syncthreads();
        if (j < 64) {
            float a = 0.f;
            #pragma unroll
            for (int d = 0; d < 64; d++) a += W_fuse[j * 192 + fofs + d] * s_e[d];
            s_t[j] = a;
        }
        __syncthreads();
        float a = 0.f;
        #pragma unroll
        for (int e = 0; e < 64; e++) a += W_ih[j * 320 + 256 + e] * s_t[e];
        float* outp = (which == 0) ? T_ut : ((which == 1) ? T_nh : T_na);
        outp[r * 192 + j] = a;
    } else {
        float a = b_ih[j];
        #pragma unroll
        for (int e = 0; e < 64; e++) a += W_ih[j * 320 + 256 + e] * b_fuse[e];
        bias0[j] = a;
        float v = 0.f;
        #pragma unroll
        for (int k = 0; k < 64; k++) v += W_ih[j * 320 + 128 + k];
        Vcorr[j] = v;
    }
}

// ---------------------------------------------------------------------------
// Kernel 2: per-question precompute. 16 questions per block so the ~91KB of
// weight rows (W_ih slice, qd_W1, dc_W1) amortize via L1/L2 instead of being
// re-streamed per question (was ~900MB of L2/L3 traffic at 1 q/block).
// ---------------------------------------------------------------------------
__global__ void k_perq(const float* __restrict__ E_q, const float* __restrict__ W_ih,
                       const float* __restrict__ qd_W1, const float* __restrict__ qd_b1,
                       const float* __restrict__ qd_W2, const float* __restrict__ qd_b2,
                       const float* __restrict__ dc_W1, const float* __restrict__ dc_b1,
                       const float* __restrict__ dc_W2, const float* __restrict__ dc_b2,
                       const int* __restrict__ q2c, const int* __restrict__ q2cm,
                       const float* __restrict__ T_c,
                       float* __restrict__ Xq, float* __restrict__ disc,
                       float* __restrict__ qds, float* __restrict__ wdk)
{
    int tid = threadIdx.x;
    __shared__ float s_qe[64], s_hid[132], s_dch[32], s_raw[4], s_rel[4], s_w[4];
    __shared__ int s_c[4], s_m[4];

    for (int qq = 0; qq < QPB; qq++) {
        int q = blockIdx.x * QPB + qq;
        if (q >= QN) break;  // uniform across block

        if (tid < 64) s_qe[tid] = E_q[q * 64 + tid];
        if (tid >= 64 && tid < 68) { s_c[tid - 64] = q2c[q * 4 + tid - 64]; s_m[tid - 64] = q2cm[q * 4 + tid - 64]; }
        __syncthreads();

        if (tid < 132) {
            float a = qd_b1[tid];
            const float* w = qd_W1 + tid * 64;
            #pragma unroll
            for (int k = 0; k < 64; k++) a += w[k] * s_qe[k];
            s_hid[tid] = fmaxf(a, 0.f);
        } else if (tid < 164) {
            int i = tid - 132;
            float a = dc_b1[i];
            const float* w = dc_W1 + i * 64;
            #pragma unroll
            for (int k = 0; k < 64; k++) a += w[k] * s_qe[k];
            s_dch[i] = fmaxf(a, 0.f);
        }
        __syncthreads();

        // concept dots: 4 groups of 32 lanes (waves 0,1), shuffle-reduced
        if (tid < 128) {
            int g = tid >> 5, l = tid & 31;
            int c = s_c[g];
            float a = 0.f;
            for (int m = l; m < 132; m += 32) a += qd_W2[c * 132 + m] * s_hid[m];
            #pragma unroll
            for (int off = 16; off; off >>= 1) a += __shfl_xor(a, off, 32);
            if (l == 0) {
                float raw = sigm(a + qd_b2[c]);
                s_raw[g] = raw;
                s_rel[g] = raw * (float)s_m[g];
            }
        } else if (tid < 160) {
            int l = tid - 128;
            float a = dc_W2[l] * s_dch[l];
            #pragma unroll
            for (int off = 16; off; off >>= 1) a += __shfl_xor(a, off, 32);
            if (l == 0) disc[q] = sigm(a + dc_b2[0]) * 10.f;
        }
        __syncthreads();

        if (tid == 0) {
            float sr = s_rel[0] + s_rel[1] + s_rel[2] + s_rel[3] + 1e-6f;
            float qsum = 0.f;
            for (int k = 0; k < 4; k++) {
                s_w[k] = s_rel[k] / sr;
                float wd = 0.f;
                if (s_m[k]) {
                    bool dup = false;
                    for (int jj = 0; jj < k; jj++)
                        if (s_m[jj] && s_c[jj] == s_c[k]) dup = true;
                    if (!dup) { wd = 1.f; qsum += s_raw[k]; }
                }
                wdk[q * 4 + k] = wd;
            }
            qds[q] = qsum;
        }
        __syncthreads();

        {
            float a = 0.f;
            const float* w = W_ih + tid * 320;
            #pragma unroll
            for (int k = 0; k < 64; k++) a += w[k] * s_qe[k];
            #pragma unroll
            for (int k = 0; k < 4; k++) a += s_w[k] * T_c[s_c[k] * 192 + tid];
            Xq[q * 192 + tid] = a;
        }
        __syncthreads();  // protect s_qe/s_w before next question overwrites
    }
}

// ---------------------------------------------------------------------------
// Kernel 3: GRU scan, 384 threads (6 waves) per sample.
//   thread pair (2 lanes) owns one gate-row: 32 weight floats/lane (8 float4)
//   half-dots combined with __shfl_xor(1) (intra-wave, no LDS)
//   each wave keeps a PRIVATE LDS copy of h and computes gates redundantly ->
//   h propagation is intra-wave (lgkmcnt-ordered), no barrier needed for it
//   pre-activations through double-buffered LDS -> ONE barrier per step
// ---------------------------------------------------------------------------
__global__ void __launch_bounds__(384, 3) k_gru(
    const float* __restrict__ W_hh, const float* __restrict__ b_hh,
    const float* __restrict__ Xq, const float* __restrict__ Tit, const float* __restrict__ Tut,
    const float* __restrict__ Tnh, const float* __restrict__ Tna,
    const float* __restrict__ b0, const float* __restrict__ vc,
    const int* __restrict__ qseq, const int* __restrict__ cseq, const int* __restrict__ itseq,
    const int* __restrict__ utseq, const int* __restrict__ nhseq, const int* __restrict__ naseq,
    float* __restrict__ latent)
{
    const int b = blockIdx.x, tid = threadIdx.x;
    const int w = tid >> 6, l = tid & 63;
    const int row = tid >> 1, half = tid & 1;   // row 0..191, half 0/1

    __shared__ float s_hw[6][64];       // per-wave private h copy
    __shared__ float s_rz[2][128];      // x+a for rows 0..127 (r,z), dbuf
    __shared__ float s_xn[2][64];       // x for rows 128..191 (n), dbuf
    __shared__ float s_an[2][64];       // a for rows 128..191 (n), dbuf
    __shared__ int s_q[TT], s_c[TT], s_it[TT], s_ut[TT], s_nh[TT], s_na[TT];

    const int base = b * TT;
    for (int i = tid; i < TT; i += 384) {
        s_q[i]  = qseq[base + i];
        s_c[i]  = cseq[base + i];
        s_it[i] = itseq[base + i];
        s_ut[i] = utseq[base + i];
        s_nh[i] = nhseq[base + i];
        s_na[i] = naseq[base + i];
    }

    // lane's half-row of W_hh: 8 float4 = 32 VGPRs
    float4 w4[8];
    {
        const float4* wp = (const float4*)(W_hh + row * 64 + half * 32);
        #pragma unroll
        for (int k = 0; k < 8; k++) w4[k] = wp[k];
    }
    #pragma unroll
    for (int k = 0; k < 8; k++)
        asm volatile("" : "+v"(w4[k].x), "+v"(w4[k].y), "+v"(w4[k].z), "+v"(w4[k].w));

    const float bh = b_hh[row], b0r = b0[row], vcr = vc[row];

    s_hw[w][l] = 0.f;
    float hl = 0.f;
    __syncthreads();   // covers index staging + h init

    // even lane gathers Xq,Tit,Tut for its row; odd lane gathers Tnh,Tna
    const float* ta = half ? Tnh : Xq;
    const float* tb = half ? Tna : Tit;
    float ga, gb, gc, cof;
    {
        int q = s_q[0], it = s_it[0], ut = s_ut[0], nh = s_nh[0], na = s_na[0];
        cof = (float)s_c[0];
        int ia = half ? nh : q, ib = half ? na : it;
        ga = ta[ia * 192 + row];
        gb = tb[ib * 192 + row];
        gc = half ? 0.f : Tut[ut * 192 + row];
    }

    int buf = 0;
    for (int t = 0; t < TT; t++) {
        // prefetch t+1 gathers (indices from LDS)
        float pa = 0.f, pb = 0.f, pc = 0.f, ncof = 0.f;
        if (t + 1 < TT) {
            int q = s_q[t + 1], it = s_it[t + 1], ut = s_ut[t + 1];
            int nh = s_nh[t + 1], nna = s_na[t + 1];
            ncof = (float)s_c[t + 1];
            int ia = half ? nh : q, ib = half ? nna : it;
            pa = ta[ia * 192 + row];
            pb = tb[ib * 192 + row];
            pc = half ? 0.f : Tut[ut * 192 + row];
        }

        // half-dot: a_half = W_hh[row][half*32 .. +32) . h[half*32 .. +32)
        float acc0 = 0.f, acc1 = 0.f;
        const float4* hp = (const float4*)(&s_hw[w][half * 32]);
        #pragma unroll
        for (int k = 0; k < 8; k += 2) {
            float4 h0 = hp[k], h1 = hp[k + 1];
            acc0 += w4[k].x     * h0.x + w4[k].y     * h0.y + w4[k].z     * h0.z + w4[k].w     * h0.w;
            acc1 += w4[k + 1].x * h1.x + w4[k + 1].y * h1.y + w4[k + 1].z * h1.z + w4[k + 1].w * h1.w;
        }
        float ah = acc0 + acc1;
        float xh = ga + gb + gc;
        float ao = __shfl_xor(ah, 1);
        float xo = __shfl_xor(xh, 1);
        if (half == 0) {
            float a = ah + ao + bh;
            float x = xh + xo + b0r + cof * vcr;
            if (row < 128) s_rz[buf][row] = x + a;
            else { s_xn[buf][row - 128] = x; s_an[buf][row - 128] = a; }
        }
        __syncthreads();   // the ONLY barrier per step

        // gates: every wave computes all 64 h elements redundantly (identical
        // inputs -> identical results), writes its own private h copy.
        float rv = s_rz[buf][l];
        float zv = s_rz[buf][64 + l];
        float xn = s_xn[buf][l];
        float an = s_an[buf][l];
        float r = sigm(rv);
        float z = sigm(zv);
        float n = tanh_fast(xn + r * an);
        hl = (1.f - z) * n + z * hl;
        s_hw[w][l] = hl;
        if (w == 0) latent[(size_t)(base + t) * 64 + l] = hl;

        ga = pa; gb = pb; gc = pc; cof = ncof;
        buf ^= 1;
    }
}

// ---------------------------------------------------------------------------
// Kernel 4: readout, one thread per output token (unchanged).
// ---------------------------------------------------------------------------
__global__ void __launch_bounds__(256, 2) k_final(
    const float* __restrict__ latent, const int* __restrict__ qseq,
    const float* __restrict__ la_W1, const float* __restrict__ la_b1,
    const float* __restrict__ la_W2, const float* __restrict__ la_b2,
    const int* __restrict__ q2c,
    const float* __restrict__ disc, const float* __restrict__ qds,
    const float* __restrict__ wdk, float* __restrict__ out)
{
    int o = blockIdx.x * blockDim.x + threadIdx.x;
    if (o >= BB * (TT - 1)) return;
    int b = o / (TT - 1), t = o - b * (TT - 1);

    const float* lat = latent + (size_t)(b * TT + t) * 64;
    float l[64];
    #pragma unroll
    for (int k4 = 0; k4 < 16; k4++) {
        float4 v = ((const float4*)lat)[k4];
        l[k4 * 4] = v.x; l[k4 * 4 + 1] = v.y; l[k4 * 4 + 2] = v.z; l[k4 * 4 + 3] = v.w;
    }

    int q = qseq[b * TT + t + 1];
    int c0 = q2c[q * 4], c1 = q2c[q * 4 + 1], c2 = q2c[q * 4 + 2], c3 = q2c[q * 4 + 3];

    float u0 = 0.f, u1 = 0.f, u2 = 0.f, u3 = 0.f;
    for (int m = 0; m < 132; m++) {
        float a = la_b1[m];
        const float* w = la_W1 + m * 64;
        #pragma unroll
        for (int k = 0; k < 64; k++) a += w[k] * l[k];
        float hm = fmaxf(a, 0.f);
        u0 += la_W2[c0 * 132 + m] * hm;
        u1 += la_W2[c1 * 132 + m] * hm;
        u2 += la_W2[c2 * 132 + m] * hm;
        u3 += la_W2[c3 * 132 + m] * hm;
    }

    float w0 = wdk[q * 4], w1 = wdk[q * 4 + 1], w2 = wdk[q * 4 + 2], w3 = wdk[q * 4 + 3];
    float us = w0 * sigm(u0 + la_b2[c0]) + w1 * sigm(u1 + la_b2[c1])
             + w2 * sigm(u2 + la_b2[c2]) + w3 * sigm(u3 + la_b2[c3]);
    float qs = qds[q];
    float y = disc[q] * (us - qs) / (qs + 1e-6f);
    out[o] = sigm(y);
}

// ---------------------------------------------------------------------------
extern "C" void kernel_launch(void* const* d_in, const int* in_sizes, int n_in,
                              void* d_out, int out_size, void* d_ws, size_t ws_size,
                              hipStream_t stream)
{
    const float* E_q    = (const float*)d_in[0];
    const float* E_c    = (const float*)d_in[1];
    const float* E_it   = (const float*)d_in[2];
    const float* E_ut   = (const float*)d_in[3];
    const float* E_nh   = (const float*)d_in[4];
    const float* W_fuse = (const float*)d_in[5];
    const float* b_fuse = (const float*)d_in[6];
    const float* W_ih   = (const float*)d_in[7];
    const float* b_ih   = (const float*)d_in[8];
    const float* W_hh   = (const float*)d_in[9];
    const float* b_hh   = (const float*)d_in[10];
    const float* qd_W1  = (const float*)d_in[11];
    const float* qd_b1  = (const float*)d_in[12];
    const float* qd_W2  = (const float*)d_in[13];
    const float* qd_b2  = (const float*)d_in[14];
    const float* la_W1  = (const float*)d_in[15];
    const float* la_b1  = (const float*)d_in[16];
    const float* la_W2  = (const float*)d_in[17];
    const float* la_b2  = (const float*)d_in[18];
    const float* dc_W1  = (const float*)d_in[19];
    const float* dc_b1  = (const float*)d_in[20];
    const float* dc_W2  = (const float*)d_in[21];
    const float* dc_b2  = (const float*)d_in[22];

    int off = (in_sizes[23] == QN * 200) ? 1 : 0;
    const int* qseq  = (const int*)d_in[23 + off];
    const int* cseq  = (const int*)d_in[24 + off];
    const int* itseq = (const int*)d_in[25 + off];
    const int* utseq = (const int*)d_in[26 + off];
    const int* nhseq = (const int*)d_in[27 + off];
    const int* naseq = (const int*)d_in[28 + off];
    const int* q2c   = (const int*)d_in[29 + off];
    const int* q2cm  = (const int*)d_in[30 + off];

    float* ws = (float*)d_ws;
    size_t o = 0;
    float* T_c  = ws + o; o += (size_t)201 * 192;
    float* Tit  = ws + o; o += (size_t)101 * 192;
    float* Tut  = ws + o; o += (size_t)101 * 192;
    float* Tnh  = ws + o; o += (size_t)101 * 192;
    float* Tna  = ws + o; o += (size_t)101 * 192;
    float* b0   = ws + o; o += 192;
    float* vc   = ws + o; o += 192;
    float* Xq   = ws + o; o += (size_t)QN * 192;
    float* disc = ws + o; o += QN;
    float* qds  = ws + o; o += QN;
    float* wdk  = ws + o; o += (size_t)QN * 4;
    float* latent = ws + o; o += (size_t)BB * TT * 64;

    float* outp = (float*)d_out;

    k_tables<<<606, 192, 0, stream>>>(E_c, E_it, E_ut, E_nh, W_fuse, b_fuse, W_ih, b_ih,
                                      T_c, Tit, Tut, Tnh, Tna, b0, vc);
    k_perq<<<(QN + QPB - 1) / QPB, 192, 0, stream>>>(E_q, W_ih, qd_W1, qd_b1, qd_W2, qd_b2,
                                                     dc_W1, dc_b1, dc_W2, dc_b2, q2c, q2cm, T_c,
                                                     Xq, disc, qds, wdk);
    k_gru<<<BB, 384, 0, stream>>>(W_hh, b_hh, Xq, Tit, Tut, Tnh, Tna, b0, vc,
                                  qseq, cseq, itseq, utseq, nhseq, naseq, latent);
    k_final<<<(BB * (TT - 1) + 255) / 256, 256, 0, stream>>>(latent, qseq, la_W1, la_b1,
                                                             la_W2, la_b2, q2c, disc, qds, wdk, outp);
}

// Round 6
// 377.045 us; speedup vs baseline: 1.2252x; 1.2252x over previous
//
#include <hip/hip_runtime.h>

// Problem constants
constexpr int QN  = 10001;   // questions (Q+1)
constexpr int BB  = 512;     // batch
constexpr int TT  = 200;     // seq len

__device__ __forceinline__ float sigm(float x) { return 1.f / (1.f + __expf(-x)); }
__device__ __forceinline__ float tanh_fast(float x) { return 1.f - 2.f / (1.f + __expf(2.f * x)); }

// ---------------------------------------------------------------------------
// Kernel 1: tiny precomputed tables (unchanged).
// ---------------------------------------------------------------------------
__global__ void k_tables(const float* __restrict__ E_c, const float* __restrict__ E_it,
                         const float* __restrict__ E_ut, const float* __restrict__ E_nh,
                         const float* __restrict__ W_fuse, const float* __restrict__ b_fuse,
                         const float* __restrict__ W_ih, const float* __restrict__ b_ih,
                         float* __restrict__ T_c, float* __restrict__ T_it,
                         float* __restrict__ T_ut, float* __restrict__ T_nh, float* __restrict__ T_na,
                         float* __restrict__ bias0, float* __restrict__ Vcorr)
{
    int blk = blockIdx.x, j = threadIdx.x; // 192 threads
    __shared__ float s_e[64];
    __shared__ float s_t[64];

    if (blk < 201) {
        if (j < 64) s_e[j] = E_c[blk * 64 + j];
        __syncthreads();
        float a = 0.f;
        #pragma unroll
        for (int k = 0; k < 64; k++) a += W_ih[j * 320 + 64 + k] * s_e[k];
        T_c[blk * 192 + j] = a;
    } else if (blk < 302) {
        int r = blk - 201;
        if (j < 64) s_e[j] = E_it[r * 64 + j];
        __syncthreads();
        float a = 0.f;
        #pragma unroll
        for (int k = 0; k < 64; k++) a += W_ih[j * 320 + 192 + k] * s_e[k];
        T_it[r * 192 + j] = a;
    } else if (blk < 605) {
        int which = (blk - 302) / 101;
        int r     = (blk - 302) % 101;
        const float* E = (which == 0) ? E_ut : E_nh;
        int fofs = which * 64;
        if (j < 64) s_e[j] = E[r * 64 + j];
        __syncthreads();
        if (j < 64) {
            float a = 0.f;
            #pragma unroll
            for (int d = 0; d < 64; d++) a += W_fuse[j * 192 + fofs + d] * s_e[d];
            s_t[j] = a;
        }
        __syncthreads();
        float a = 0.f;
        #pragma unroll
        for (int e = 0; e < 64; e++) a += W_ih[j * 320 + 256 + e] * s_t[e];
        float* outp = (which == 0) ? T_ut : ((which == 1) ? T_nh : T_na);
        outp[r * 192 + j] = a;
    } else {
        float a = b_ih[j];
        #pragma unroll
        for (int e = 0; e < 64; e++) a += W_ih[j * 320 + 256 + e] * b_fuse[e];
        bias0[j] = a;
        float v = 0.f;
        #pragma unroll
        for (int k = 0; k < 64; k++) v += W_ih[j * 320 + 128 + k];
        Vcorr[j] = v;
    }
}

// ---------------------------------------------------------------------------
// Kernel 2: per-question precompute (r4 form: one question per block).
// ---------------------------------------------------------------------------
__global__ void k_perq(const float* __restrict__ E_q, const float* __restrict__ W_ih,
                       const float* __restrict__ qd_W1, const float* __restrict__ qd_b1,
                       const float* __restrict__ qd_W2, const float* __restrict__ qd_b2,
                       const float* __restrict__ dc_W1, const float* __restrict__ dc_b1,
                       const float* __restrict__ dc_W2, const float* __restrict__ dc_b2,
                       const int* __restrict__ q2c, const int* __restrict__ q2cm,
                       const float* __restrict__ T_c,
                       float* __restrict__ Xq, float* __restrict__ disc,
                       float* __restrict__ qds, float* __restrict__ wdk)
{
    int q = blockIdx.x, tid = threadIdx.x;
    __shared__ float s_qe[64], s_hid[132], s_dch[32], s_raw[4], s_rel[4], s_w[4];
    __shared__ int s_c[4], s_m[4];

    if (tid < 64) s_qe[tid] = E_q[q * 64 + tid];
    if (tid >= 64 && tid < 68) { s_c[tid - 64] = q2c[q * 4 + tid - 64]; s_m[tid - 64] = q2cm[q * 4 + tid - 64]; }
    __syncthreads();

    if (tid < 132) {
        float a = qd_b1[tid];
        const float* w = qd_W1 + tid * 64;
        #pragma unroll
        for (int k = 0; k < 64; k++) a += w[k] * s_qe[k];
        s_hid[tid] = fmaxf(a, 0.f);
    } else if (tid < 164) {
        int i = tid - 132;
        float a = dc_b1[i];
        const float* w = dc_W1 + i * 64;
        #pragma unroll
        for (int k = 0; k < 64; k++) a += w[k] * s_qe[k];
        s_dch[i] = fmaxf(a, 0.f);
    }
    __syncthreads();

    // concept dots: 4 groups of 32 lanes (waves 0,1), shuffle-reduced
    if (tid < 128) {
        int g = tid >> 5, l = tid & 31;
        int c = s_c[g];
        float a = 0.f;
        for (int m = l; m < 132; m += 32) a += qd_W2[c * 132 + m] * s_hid[m];
        #pragma unroll
        for (int off = 16; off; off >>= 1) a += __shfl_xor(a, off, 32);
        if (l == 0) {
            float raw = sigm(a + qd_b2[c]);
            s_raw[g] = raw;
            s_rel[g] = raw * (float)s_m[g];
        }
    } else if (tid < 160) {
        int l = tid - 128;
        float a = dc_W2[l] * s_dch[l];
        #pragma unroll
        for (int off = 16; off; off >>= 1) a += __shfl_xor(a, off, 32);
        if (l == 0) disc[q] = sigm(a + dc_b2[0]) * 10.f;
    }
    __syncthreads();

    if (tid == 0) {
        float sr = s_rel[0] + s_rel[1] + s_rel[2] + s_rel[3] + 1e-6f;
        float qsum = 0.f;
        for (int k = 0; k < 4; k++) {
            s_w[k] = s_rel[k] / sr;
            float wd = 0.f;
            if (s_m[k]) {
                bool dup = false;
                for (int jj = 0; jj < k; jj++)
                    if (s_m[jj] && s_c[jj] == s_c[k]) dup = true;
                if (!dup) { wd = 1.f; qsum += s_raw[k]; }
            }
            wdk[q * 4 + k] = wd;
        }
        qds[q] = qsum;
    }
    __syncthreads();

    {
        float a = 0.f;
        const float* w = W_ih + tid * 320;
        #pragma unroll
        for (int k = 0; k < 64; k++) a += w[k] * s_qe[k];
        #pragma unroll
        for (int k = 0; k < 4; k++) a += s_w[k] * T_c[s_c[k] * 192 + tid];
        Xq[q * 192 + tid] = a;
    }
}

// ---------------------------------------------------------------------------
// Kernel 3: GRU scan, 192 threads (3 waves) per sample, lane j owns gate-row j.
// amdgpu_waves_per_eu(1,2): caps the SCHEDULER'S occupancy TARGET at 2
// waves/EU (exactly what the 512-block grid can use: 2 blocks x 3 waves /CU).
// Rounds 2-5 showed the GCN scheduler remats the invariant W_hh loads into
// the loop chasing a default high-occupancy target launch_bounds can't lower
// (launch_bounds' 2nd arg only sets the MIN-waves floor / register ceiling).
// ---------------------------------------------------------------------------
__global__ void
__launch_bounds__(192)
__attribute__((amdgpu_waves_per_eu(1, 2)))
k_gru(
    const float* __restrict__ W_hh, const float* __restrict__ b_hh,
    const float* __restrict__ Xq, const float* __restrict__ Tit, const float* __restrict__ Tut,
    const float* __restrict__ Tnh, const float* __restrict__ Tna,
    const float* __restrict__ b0, const float* __restrict__ vc,
    const int* __restrict__ qseq, const int* __restrict__ cseq, const int* __restrict__ itseq,
    const int* __restrict__ utseq, const int* __restrict__ nhseq, const int* __restrict__ naseq,
    float* __restrict__ latent)
{
    int b = blockIdx.x, j = threadIdx.x;
    __shared__ float s_h[64];
    __shared__ float s_a[192];
    __shared__ float s_x[192];
    __shared__ int s_q[TT], s_c[TT], s_it[TT], s_ut[TT], s_nh[TT], s_na[TT];

    const int base = b * TT;
    for (int i = j; i < TT; i += 192) {
        s_q[i]  = qseq[base + i];
        s_c[i]  = cseq[base + i];
        s_it[i] = itseq[base + i];
        s_ut[i] = utseq[base + i];
        s_nh[i] = nhseq[base + i];
        s_na[i] = naseq[base + i];
    }

    // lane j's gate row of W_hh: 16 float4 = 64 VGPRs, resident
    float4 w4[16];
    {
        const float4* wp = (const float4*)(W_hh + j * 64);
        #pragma unroll
        for (int k = 0; k < 16; k++) w4[k] = wp[k];
    }
    #pragma unroll
    for (int k = 0; k < 16; k++)
        asm volatile("" : "+v"(w4[k].x), "+v"(w4[k].y), "+v"(w4[k].z), "+v"(w4[k].w));

    float bh = b_hh[j], b0j = b0[j], vcj = vc[j];

    if (j < 64) s_h[j] = 0.f;
    float hi = 0.f;
    __syncthreads();  // covers s_idx + s_h init

    // t=0 gathers
    float g0, g1, g2, g3, g4, cof;
    {
        int q = s_q[0], it = s_it[0], ut = s_ut[0], nh = s_nh[0], na = s_na[0];
        cof = (float)s_c[0];
        g0 = Xq[q * 192 + j];  g1 = Tit[it * 192 + j]; g2 = Tut[ut * 192 + j];
        g3 = Tnh[nh * 192 + j]; g4 = Tna[na * 192 + j];
    }

    for (int t = 0; t < TT; t++) {
        // prefetch t+1 gathers (indices from LDS -> no global index chain)
        float n0 = 0.f, n1 = 0.f, n2 = 0.f, n3 = 0.f, n4 = 0.f, ncof = 0.f;
        if (t + 1 < TT) {
            int q = s_q[t + 1], it = s_it[t + 1], ut = s_ut[t + 1];
            int nh = s_nh[t + 1], na = s_na[t + 1];
            ncof = (float)s_c[t + 1];
            n0 = Xq[q * 192 + j];  n1 = Tit[it * 192 + j]; n2 = Tut[ut * 192 + j];
            n3 = Tnh[nh * 192 + j]; n4 = Tna[na * 192 + j];
        }

        // a[j] = W_hh[j,:] . h + b_hh[j]  (h broadcast from LDS, 4 accumulators)
        float a0 = 0.f, a1 = 0.f, a2 = 0.f, a3 = 0.f;
        const float4* h4 = (const float4*)s_h;
        #pragma unroll
        for (int k = 0; k < 16; k += 4) {
            float4 ha = h4[k], hb = h4[k + 1], hc = h4[k + 2], hd = h4[k + 3];
            a0 += w4[k].x     * ha.x + w4[k].y     * ha.y + w4[k].z     * ha.z + w4[k].w     * ha.w;
            a1 += w4[k + 1].x * hb.x + w4[k + 1].y * hb.y + w4[k + 1].z * hb.z + w4[k + 1].w * hb.w;
            a2 += w4[k + 2].x * hc.x + w4[k + 2].y * hc.y + w4[k + 2].z * hc.z + w4[k + 2].w * hc.w;
            a3 += w4[k + 3].x * hd.x + w4[k + 3].y * hd.y + w4[k + 3].z * hd.z + w4[k + 3].w * hd.w;
        }
        float a = ((a0 + a1) + (a2 + a3)) + bh;
        float x = b0j + cof * vcj + (((g0 + g1) + (g2 + g3)) + g4);
        s_a[j] = a;
        s_x[j] = x;
        __syncthreads();

        if (j < 64) {
            float r = sigm(s_x[j] + s_a[j]);
            float z = sigm(s_x[64 + j] + s_a[64 + j]);
            float n = tanh_fast(s_x[128 + j] + r * s_a[128 + j]);
            hi = (1.f - z) * n + z * hi;
            s_h[j] = hi;
            latent[(size_t)(base + t) * 64 + j] = hi;
        }
        __syncthreads();

        g0 = n0; g1 = n1; g2 = n2; g3 = n3; g4 = n4; cof = ncof;
    }
}

// ---------------------------------------------------------------------------
// Kernel 4: readout, one thread per output token (unchanged).
// ---------------------------------------------------------------------------
__global__ void __launch_bounds__(256, 2) k_final(
    const float* __restrict__ latent, const int* __restrict__ qseq,
    const float* __restrict__ la_W1, const float* __restrict__ la_b1,
    const float* __restrict__ la_W2, const float* __restrict__ la_b2,
    const int* __restrict__ q2c,
    const float* __restrict__ disc, const float* __restrict__ qds,
    const float* __restrict__ wdk, float* __restrict__ out)
{
    int o = blockIdx.x * blockDim.x + threadIdx.x;
    if (o >= BB * (TT - 1)) return;
    int b = o / (TT - 1), t = o - b * (TT - 1);

    const float* lat = latent + (size_t)(b * TT + t) * 64;
    float l[64];
    #pragma unroll
    for (int k4 = 0; k4 < 16; k4++) {
        float4 v = ((const float4*)lat)[k4];
        l[k4 * 4] = v.x; l[k4 * 4 + 1] = v.y; l[k4 * 4 + 2] = v.z; l[k4 * 4 + 3] = v.w;
    }

    int q = qseq[b * TT + t + 1];
    int c0 = q2c[q * 4], c1 = q2c[q * 4 + 1], c2 = q2c[q * 4 + 2], c3 = q2c[q * 4 + 3];

    float u0 = 0.f, u1 = 0.f, u2 = 0.f, u3 = 0.f;
    for (int m = 0; m < 132; m++) {
        float a = la_b1[m];
        const float* w = la_W1 + m * 64;
        #pragma unroll
        for (int k = 0; k < 64; k++) a += w[k] * l[k];
        float hm = fmaxf(a, 0.f);
        u0 += la_W2[c0 * 132 + m] * hm;
        u1 += la_W2[c1 * 132 + m] * hm;
        u2 += la_W2[c2 * 132 + m] * hm;
        u3 += la_W2[c3 * 132 + m] * hm;
    }

    float w0 = wdk[q * 4], w1 = wdk[q * 4 + 1], w2 = wdk[q * 4 + 2], w3 = wdk[q * 4 + 3];
    float us = w0 * sigm(u0 + la_b2[c0]) + w1 * sigm(u1 + la_b2[c1])
             + w2 * sigm(u2 + la_b2[c2]) + w3 * sigm(u3 + la_b2[c3]);
    float qs = qds[q];
    float y = disc[q] * (us - qs) / (qs + 1e-6f);
    out[o] = sigm(y);
}

// ---------------------------------------------------------------------------
extern "C" void kernel_launch(void* const* d_in, const int* in_sizes, int n_in,
                              void* d_out, int out_size, void* d_ws, size_t ws_size,
                              hipStream_t stream)
{
    const float* E_q    = (const float*)d_in[0];
    const float* E_c    = (const float*)d_in[1];
    const float* E_it   = (const float*)d_in[2];
    const float* E_ut   = (const float*)d_in[3];
    const float* E_nh   = (const float*)d_in[4];
    const float* W_fuse = (const float*)d_in[5];
    const float* b_fuse = (const float*)d_in[6];
    const float* W_ih   = (const float*)d_in[7];
    const float* b_ih   = (const float*)d_in[8];
    const float* W_hh   = (const float*)d_in[9];
    const float* b_hh   = (const float*)d_in[10];
    const float* qd_W1  = (const float*)d_in[11];
    const float* qd_b1  = (const float*)d_in[12];
    const float* qd_W2  = (const float*)d_in[13];
    const float* qd_b2  = (const float*)d_in[14];
    const float* la_W1  = (const float*)d_in[15];
    const float* la_b1  = (const float*)d_in[16];
    const float* la_W2  = (const float*)d_in[17];
    const float* la_b2  = (const float*)d_in[18];
    const float* dc_W1  = (const float*)d_in[19];
    const float* dc_b1  = (const float*)d_in[20];
    const float* dc_W2  = (const float*)d_in[21];
    const float* dc_b2  = (const float*)d_in[22];

    int off = (in_sizes[23] == QN * 200) ? 1 : 0;
    const int* qseq  = (const int*)d_in[23 + off];
    const int* cseq  = (const int*)d_in[24 + off];
    const int* itseq = (const int*)d_in[25 + off];
    const int* utseq = (const int*)d_in[26 + off];
    const int* nhseq = (const int*)d_in[27 + off];
    const int* naseq = (const int*)d_in[28 + off];
    const int* q2c   = (const int*)d_in[29 + off];
    const int* q2cm  = (const int*)d_in[30 + off];

    float* ws = (float*)d_ws;
    size_t o = 0;
    float* T_c  = ws + o; o += (size_t)201 * 192;
    float* Tit  = ws + o; o += (size_t)101 * 192;
    float* Tut  = ws + o; o += (size_t)101 * 192;
    float* Tnh  = ws + o; o += (size_t)101 * 192;
    float* Tna  = ws + o; o += (size_t)101 * 192;
    float* b0   = ws + o; o += 192;
    float* vc   = ws + o; o += 192;
    float* Xq   = ws + o; o += (size_t)QN * 192;
    float* disc = ws + o; o += QN;
    float* qds  = ws + o; o += QN;
    float* wdk  = ws + o; o += (size_t)QN * 4;
    float* latent = ws + o; o += (size_t)BB * TT * 64;

    float* outp = (float*)d_out;

    k_tables<<<606, 192, 0, stream>>>(E_c, E_it, E_ut, E_nh, W_fuse, b_fuse, W_ih, b_ih,
                                      T_c, Tit, Tut, Tnh, Tna, b0, vc);
    k_perq<<<QN, 192, 0, stream>>>(E_q, W_ih, qd_W1, qd_b1, qd_W2, qd_b2,
                                   dc_W1, dc_b1, dc_W2, dc_b2, q2c, q2cm, T_c,
                                   Xq, disc, qds, wdk);
    k_gru<<<BB, 192, 0, stream>>>(W_hh, b_hh, Xq, Tit, Tut, Tnh, Tna, b0, vc,
                                  qseq, cseq, itseq, utseq, nhseq, naseq, latent);
    k_final<<<(BB * (TT - 1) + 255) / 256, 256, 0, stream>>>(latent, qseq, la_W1, la_b1,
                                                             la_W2, la_b2, q2c, disc, qds, wdk, outp);
}

// Round 7
// 371.300 us; speedup vs baseline: 1.2442x; 1.0155x over previous
//
#include <hip/hip_runtime.h>

// Problem constants
constexpr int QN  = 10001;   // questions (Q+1)
constexpr int BB  = 512;     // batch
constexpr int TT  = 200;     // seq len

__device__ __forceinline__ float sigm(float x) { return 1.f / (1.f + __expf(-x)); }
__device__ __forceinline__ float tanh_fast(float x) { return 1.f - 2.f / (1.f + __expf(2.f * x)); }

// RTNE float -> bf16 bits (weights are normal values; no NaN handling needed)
__device__ __forceinline__ unsigned bf16r(float f) {
    unsigned x = __float_as_uint(f);
    return (x + 0x7fffu + ((x >> 16) & 1u)) >> 16;
}

// ---------------------------------------------------------------------------
// Kernel 1: tiny precomputed tables (unchanged).
// ---------------------------------------------------------------------------
__global__ void k_tables(const float* __restrict__ E_c, const float* __restrict__ E_it,
                         const float* __restrict__ E_ut, const float* __restrict__ E_nh,
                         const float* __restrict__ W_fuse, const float* __restrict__ b_fuse,
                         const float* __restrict__ W_ih, const float* __restrict__ b_ih,
                         float* __restrict__ T_c, float* __restrict__ T_it,
                         float* __restrict__ T_ut, float* __restrict__ T_nh, float* __restrict__ T_na,
                         float* __restrict__ bias0, float* __restrict__ Vcorr)
{
    int blk = blockIdx.x, j = threadIdx.x; // 192 threads
    __shared__ float s_e[64];
    __shared__ float s_t[64];

    if (blk < 201) {
        if (j < 64) s_e[j] = E_c[blk * 64 + j];
        __syncthreads();
        float a = 0.f;
        #pragma unroll
        for (int k = 0; k < 64; k++) a += W_ih[j * 320 + 64 + k] * s_e[k];
        T_c[blk * 192 + j] = a;
    } else if (blk < 302) {
        int r = blk - 201;
        if (j < 64) s_e[j] = E_it[r * 64 + j];
        __syncthreads();
        float a = 0.f;
        #pragma unroll
        for (int k = 0; k < 64; k++) a += W_ih[j * 320 + 192 + k] * s_e[k];
        T_it[r * 192 + j] = a;
    } else if (blk < 605) {
        int which = (blk - 302) / 101;
        int r     = (blk - 302) % 101;
        const float* E = (which == 0) ? E_ut : E_nh;
        int fofs = which * 64;
        if (j < 64) s_e[j] = E[r * 64 + j];
        __syncthreads();
        if (j < 64) {
            float a = 0.f;
            #pragma unroll
            for (int d = 0; d < 64; d++) a += W_fuse[j * 192 + fofs + d] * s_e[d];
            s_t[j] = a;
        }
        __syncthreads();
        float a = 0.f;
        #pragma unroll
        for (int e = 0; e < 64; e++) a += W_ih[j * 320 + 256 + e] * s_t[e];
        float* outp = (which == 0) ? T_ut : ((which == 1) ? T_nh : T_na);
        outp[r * 192 + j] = a;
    } else {
        float a = b_ih[j];
        #pragma unroll
        for (int e = 0; e < 64; e++) a += W_ih[j * 320 + 256 + e] * b_fuse[e];
        bias0[j] = a;
        float v = 0.f;
        #pragma unroll
        for (int k = 0; k < 64; k++) v += W_ih[j * 320 + 128 + k];
        Vcorr[j] = v;
    }
}

// ---------------------------------------------------------------------------
// Kernel 2: per-question precompute (unchanged).
// ---------------------------------------------------------------------------
__global__ void k_perq(const float* __restrict__ E_q, const float* __restrict__ W_ih,
                       const float* __restrict__ qd_W1, const float* __restrict__ qd_b1,
                       const float* __restrict__ qd_W2, const float* __restrict__ qd_b2,
                       const float* __restrict__ dc_W1, const float* __restrict__ dc_b1,
                       const float* __restrict__ dc_W2, const float* __restrict__ dc_b2,
                       const int* __restrict__ q2c, const int* __restrict__ q2cm,
                       const float* __restrict__ T_c,
                       float* __restrict__ Xq, float* __restrict__ disc,
                       float* __restrict__ qds, float* __restrict__ wdk)
{
    int q = blockIdx.x, tid = threadIdx.x;
    __shared__ float s_qe[64], s_hid[132], s_dch[32], s_raw[4], s_rel[4], s_w[4];
    __shared__ int s_c[4], s_m[4];

    if (tid < 64) s_qe[tid] = E_q[q * 64 + tid];
    if (tid >= 64 && tid < 68) { s_c[tid - 64] = q2c[q * 4 + tid - 64]; s_m[tid - 64] = q2cm[q * 4 + tid - 64]; }
    __syncthreads();

    if (tid < 132) {
        float a = qd_b1[tid];
        const float* w = qd_W1 + tid * 64;
        #pragma unroll
        for (int k = 0; k < 64; k++) a += w[k] * s_qe[k];
        s_hid[tid] = fmaxf(a, 0.f);
    } else if (tid < 164) {
        int i = tid - 132;
        float a = dc_b1[i];
        const float* w = dc_W1 + i * 64;
        #pragma unroll
        for (int k = 0; k < 64; k++) a += w[k] * s_qe[k];
        s_dch[i] = fmaxf(a, 0.f);
    }
    __syncthreads();

    if (tid < 128) {
        int g = tid >> 5, l = tid & 31;
        int c = s_c[g];
        float a = 0.f;
        for (int m = l; m < 132; m += 32) a += qd_W2[c * 132 + m] * s_hid[m];
        #pragma unroll
        for (int off = 16; off; off >>= 1) a += __shfl_xor(a, off, 32);
        if (l == 0) {
            float raw = sigm(a + qd_b2[c]);
            s_raw[g] = raw;
            s_rel[g] = raw * (float)s_m[g];
        }
    } else if (tid < 160) {
        int l = tid - 128;
        float a = dc_W2[l] * s_dch[l];
        #pragma unroll
        for (int off = 16; off; off >>= 1) a += __shfl_xor(a, off, 32);
        if (l == 0) disc[q] = sigm(a + dc_b2[0]) * 10.f;
    }
    __syncthreads();

    if (tid == 0) {
        float sr = s_rel[0] + s_rel[1] + s_rel[2] + s_rel[3] + 1e-6f;
        float qsum = 0.f;
        for (int k = 0; k < 4; k++) {
            s_w[k] = s_rel[k] / sr;
            float wd = 0.f;
            if (s_m[k]) {
                bool dup = false;
                for (int jj = 0; jj < k; jj++)
                    if (s_m[jj] && s_c[jj] == s_c[k]) dup = true;
                if (!dup) { wd = 1.f; qsum += s_raw[k]; }
            }
            wdk[q * 4 + k] = wd;
        }
        qds[q] = qsum;
    }
    __syncthreads();

    {
        float a = 0.f;
        const float* w = W_ih + tid * 320;
        #pragma unroll
        for (int k = 0; k < 64; k++) a += w[k] * s_qe[k];
        #pragma unroll
        for (int k = 0; k < 4; k++) a += s_w[k] * T_c[s_c[k] * 192 + tid];
        Xq[q * 192 + tid] = a;
    }
}

// ---------------------------------------------------------------------------
// Kernel 3: GRU scan v7. 192 threads (3 waves), lane owns gate-row tid.
//  - W_hh row packed to bf16 pairs: 32 VGPRs (fits the ~88 budget the
//    allocator actually grants; pack chain is not trivially remat-able).
//  - Every wave computes all 64 gates redundantly from shared dbuf'd
//    pre-activations + keeps a PRIVATE h copy -> ONE barrier per step,
//    h->h chain is intra-wave (lgkmcnt only), no wave0 serialization.
//  - Gathers prefetched 2 steps ahead (covers ~600cy L3 latency on Xq).
// ---------------------------------------------------------------------------
__global__ void
__launch_bounds__(192)
__attribute__((amdgpu_waves_per_eu(1, 2)))
k_gru(
    const float* __restrict__ W_hh, const float* __restrict__ b_hh,
    const float* __restrict__ Xq, const float* __restrict__ Tit, const float* __restrict__ Tut,
    const float* __restrict__ Tnh, const float* __restrict__ Tna,
    const float* __restrict__ b0, const float* __restrict__ vc,
    const int* __restrict__ qseq, const int* __restrict__ cseq, const int* __restrict__ itseq,
    const int* __restrict__ utseq, const int* __restrict__ nhseq, const int* __restrict__ naseq,
    float* __restrict__ latent)
{
    const int tid = threadIdx.x, b = blockIdx.x;
    const int l = tid & 63, w = tid >> 6;

    __shared__ float s_hw[3][64];    // per-wave private h copy
    __shared__ float s_rz[2][128];   // x+a for rows 0..127, double-buffered
    __shared__ float s_xn[2][64];    // x for rows 128..191
    __shared__ float s_an[2][64];    // a for rows 128..191
    __shared__ int s_q[TT], s_c[TT], s_it[TT], s_ut[TT], s_nh[TT], s_na[TT];

    const int base = b * TT;
    for (int i = tid; i < TT; i += 192) {
        s_q[i]  = qseq[base + i];
        s_c[i]  = cseq[base + i];
        s_it[i] = itseq[base + i];
        s_ut[i] = utseq[base + i];
        s_nh[i] = nhseq[base + i];
        s_na[i] = naseq[base + i];
    }

    // lane's gate-row of W_hh as 32 packed bf16 pairs (32 VGPRs)
    unsigned w2[32];
    {
        const float4* wp = (const float4*)(W_hh + tid * 64);
        #pragma unroll
        for (int k = 0; k < 16; k++) {
            float4 v = wp[k];
            w2[2 * k]     = (bf16r(v.y) << 16) | bf16r(v.x);
            w2[2 * k + 1] = (bf16r(v.w) << 16) | bf16r(v.z);
        }
    }
    #pragma unroll
    for (int k = 0; k < 32; k++) asm volatile("" : "+v"(w2[k]));

    const float bh = b_hh[tid], b0j = b0[tid], vcj = vc[tid];

    s_hw[w][l] = 0.f;
    float hi = 0.f;
    __syncthreads();   // covers idx staging + h init

    // depth-2 prefetch pipeline: g = step t, p = step t+1
    float g0, g1, g2, g3, g4, cg;
    float p0, p1, p2, p3, p4, cp;
    {
        int q = s_q[0], it = s_it[0], ut = s_ut[0], nh = s_nh[0], na = s_na[0];
        cg = (float)s_c[0];
        g0 = Xq[q * 192 + tid];  g1 = Tit[it * 192 + tid]; g2 = Tut[ut * 192 + tid];
        g3 = Tnh[nh * 192 + tid]; g4 = Tna[na * 192 + tid];
    }
    {
        int q = s_q[1], it = s_it[1], ut = s_ut[1], nh = s_nh[1], na = s_na[1];
        cp = (float)s_c[1];
        p0 = Xq[q * 192 + tid];  p1 = Tit[it * 192 + tid]; p2 = Tut[ut * 192 + tid];
        p3 = Tnh[nh * 192 + tid]; p4 = Tna[na * 192 + tid];
    }

    const float4* hp = (const float4*)s_hw[w];
    int buf = 0;
    for (int t = 0; t < TT; t++) {
        // issue loads for step t+2
        float q0 = 0.f, q1 = 0.f, q2 = 0.f, q3 = 0.f, q4 = 0.f, cq = 0.f;
        if (t + 2 < TT) {
            int q = s_q[t + 2], it = s_it[t + 2], ut = s_ut[t + 2];
            int nh = s_nh[t + 2], na = s_na[t + 2];
            cq = (float)s_c[t + 2];
            q0 = Xq[q * 192 + tid];  q1 = Tit[it * 192 + tid]; q2 = Tut[ut * 192 + tid];
            q3 = Tnh[nh * 192 + tid]; q4 = Tna[na * 192 + tid];
        }

        // a[tid] = W_hh[tid,:] . h + b_hh[tid]; h broadcast from OWN wave copy
        float a0 = 0.f, a1 = 0.f, a2 = 0.f, a3 = 0.f;
        #pragma unroll
        for (int k = 0; k < 16; k++) {
            float4 h = hp[k];
            unsigned ua = w2[2 * k], ub = w2[2 * k + 1];
            a0 += __uint_as_float(ua << 16)          * h.x;
            a1 += __uint_as_float(ua & 0xffff0000u)  * h.y;
            a2 += __uint_as_float(ub << 16)          * h.z;
            a3 += __uint_as_float(ub & 0xffff0000u)  * h.w;
        }
        float a = ((a0 + a1) + (a2 + a3)) + bh;
        float x = b0j + cg * vcj + (((g0 + g1) + (g2 + g3)) + g4);
        if (tid < 128) s_rz[buf][tid] = x + a;              // waves 0,1: uniform
        else { s_xn[buf][tid - 128] = x; s_an[buf][tid - 128] = a; }  // wave 2
        __syncthreads();   // the ONLY barrier per step

        // gates: all 3 waves redundantly (identical inputs -> identical h)
        float rv  = s_rz[buf][l];
        float zv  = s_rz[buf][64 + l];
        float xnv = s_xn[buf][l];
        float anv = s_an[buf][l];
        float r = sigm(rv);
        float z = sigm(zv);
        float n = tanh_fast(xnv + r * anv);
        hi = (1.f - z) * n + z * hi;
        s_hw[w][l] = hi;                       // own copy; intra-wave dep only
        if (w == 0) latent[(size_t)(base + t) * 64 + l] = hi;

        g0 = p0; g1 = p1; g2 = p2; g3 = p3; g4 = p4; cg = cp;
        p0 = q0; p1 = q1; p2 = q2; p3 = q3; p4 = q4; cp = cq;
        buf ^= 1;
    }
}

// ---------------------------------------------------------------------------
// Kernel 4: readout, one thread per output token (unchanged).
// ---------------------------------------------------------------------------
__global__ void __launch_bounds__(256, 2) k_final(
    const float* __restrict__ latent, const int* __restrict__ qseq,
    const float* __restrict__ la_W1, const float* __restrict__ la_b1,
    const float* __restrict__ la_W2, const float* __restrict__ la_b2,
    const int* __restrict__ q2c,
    const float* __restrict__ disc, const float* __restrict__ qds,
    const float* __restrict__ wdk, float* __restrict__ out)
{
    int o = blockIdx.x * blockDim.x + threadIdx.x;
    if (o >= BB * (TT - 1)) return;
    int b = o / (TT - 1), t = o - b * (TT - 1);

    const float* lat = latent + (size_t)(b * TT + t) * 64;
    float l[64];
    #pragma unroll
    for (int k4 = 0; k4 < 16; k4++) {
        float4 v = ((const float4*)lat)[k4];
        l[k4 * 4] = v.x; l[k4 * 4 + 1] = v.y; l[k4 * 4 + 2] = v.z; l[k4 * 4 + 3] = v.w;
    }

    int q = qseq[b * TT + t + 1];
    int c0 = q2c[q * 4], c1 = q2c[q * 4 + 1], c2 = q2c[q * 4 + 2], c3 = q2c[q * 4 + 3];

    float u0 = 0.f, u1 = 0.f, u2 = 0.f, u3 = 0.f;
    for (int m = 0; m < 132; m++) {
        float a = la_b1[m];
        const float* w = la_W1 + m * 64;
        #pragma unroll
        for (int k = 0; k < 64; k++) a += w[k] * l[k];
        float hm = fmaxf(a, 0.f);
        u0 += la_W2[c0 * 132 + m] * hm;
        u1 += la_W2[c1 * 132 + m] * hm;
        u2 += la_W2[c2 * 132 + m] * hm;
        u3 += la_W2[c3 * 132 + m] * hm;
    }

    float w0 = wdk[q * 4], w1 = wdk[q * 4 + 1], w2 = wdk[q * 4 + 2], w3 = wdk[q * 4 + 3];
    float us = w0 * sigm(u0 + la_b2[c0]) + w1 * sigm(u1 + la_b2[c1])
             + w2 * sigm(u2 + la_b2[c2]) + w3 * sigm(u3 + la_b2[c3]);
    float qs = qds[q];
    float y = disc[q] * (us - qs) / (qs + 1e-6f);
    out[o] = sigm(y);
}

// ---------------------------------------------------------------------------
extern "C" void kernel_launch(void* const* d_in, const int* in_sizes, int n_in,
                              void* d_out, int out_size, void* d_ws, size_t ws_size,
                              hipStream_t stream)
{
    const float* E_q    = (const float*)d_in[0];
    const float* E_c    = (const float*)d_in[1];
    const float* E_it   = (const float*)d_in[2];
    const float* E_ut   = (const float*)d_in[3];
    const float* E_nh   = (const float*)d_in[4];
    const float* W_fuse = (const float*)d_in[5];
    const float* b_fuse = (const float*)d_in[6];
    const float* W_ih   = (const float*)d_in[7];
    const float* b_ih   = (const float*)d_in[8];
    const float* W_hh   = (const float*)d_in[9];
    const float* b_hh   = (const float*)d_in[10];
    const float* qd_W1  = (const float*)d_in[11];
    const float* qd_b1  = (const float*)d_in[12];
    const float* qd_W2  = (const float*)d_in[13];
    const float* qd_b2  = (const float*)d_in[14];
    const float* la_W1  = (const float*)d_in[15];
    const float* la_b1  = (const float*)d_in[16];
    const float* la_W2  = (const float*)d_in[17];
    const float* la_b2  = (const float*)d_in[18];
    const float* dc_W1  = (const float*)d_in[19];
    const float* dc_b1  = (const float*)d_in[20];
    const float* dc_W2  = (const float*)d_in[21];
    const float* dc_b2  = (const float*)d_in[22];

    int off = (in_sizes[23] == QN * 200) ? 1 : 0;
    const int* qseq  = (const int*)d_in[23 + off];
    const int* cseq  = (const int*)d_in[24 + off];
    const int* itseq = (const int*)d_in[25 + off];
    const int* utseq = (const int*)d_in[26 + off];
    const int* nhseq = (const int*)d_in[27 + off];
    const int* naseq = (const int*)d_in[28 + off];
    const int* q2c   = (const int*)d_in[29 + off];
    const int* q2cm  = (const int*)d_in[30 + off];

    float* ws = (float*)d_ws;
    size_t o = 0;
    float* T_c  = ws + o; o += (size_t)201 * 192;
    float* Tit  = ws + o; o += (size_t)101 * 192;
    float* Tut  = ws + o; o += (size_t)101 * 192;
    float* Tnh  = ws + o; o += (size_t)101 * 192;
    float* Tna  = ws + o; o += (size_t)101 * 192;
    float* b0   = ws + o; o += 192;
    float* vc   = ws + o; o += 192;
    float* Xq   = ws + o; o += (size_t)QN * 192;
    float* disc = ws + o; o += QN;
    float* qds  = ws + o; o += QN;
    float* wdk  = ws + o; o += (size_t)QN * 4;
    float* latent = ws + o; o += (size_t)BB * TT * 64;

    float* outp = (float*)d_out;

    k_tables<<<606, 192, 0, stream>>>(E_c, E_it, E_ut, E_nh, W_fuse, b_fuse, W_ih, b_ih,
                                      T_c, Tit, Tut, Tnh, Tna, b0, vc);
    k_perq<<<QN, 192, 0, stream>>>(E_q, W_ih, qd_W1, qd_b1, qd_W2, qd_b2,
                                   dc_W1, dc_b1, dc_W2, dc_b2, q2c, q2cm, T_c,
                                   Xq, disc, qds, wdk);
    k_gru<<<BB, 192, 0, stream>>>(W_hh, b_hh, Xq, Tit, Tut, Tnh, Tna, b0, vc,
                                  qseq, cseq, itseq, utseq, nhseq, naseq, latent);
    k_final<<<(BB * (TT - 1) + 255) / 256, 256, 0, stream>>>(latent, qseq, la_W1, la_b1,
                                                             la_W2, la_b2, q2c, disc, qds, wdk, outp);
}